// Round 1
// baseline (70.479 us; speedup 1.0000x reference)
//
#include <hip/hip_runtime.h>
#include <hip/hip_bf16.h>

#define BB 16
#define LCTX 2048
#define DDIM 1024
#define QDIM 1024
#define HDIM 256
#define NEGV -10000.0f

typedef __attribute__((ext_vector_type(8))) short short8;
typedef __attribute__((ext_vector_type(4))) float f32x4;

__device__ inline unsigned short f2bf(float x) {
    unsigned int u = __float_as_uint(x);
    unsigned int r = (u + 0x7fffu + ((u >> 16) & 1u)) >> 16;
    return (unsigned short)r;
}

// ---------------- K0a: qproj[b][h] = query[b] . Wq[h] + b1[h] ----------------
__global__ __launch_bounds__(256) void k_qproj(const float* __restrict__ query,
                                               const float* __restrict__ W1,
                                               const float* __restrict__ b1,
                                               float* __restrict__ qproj) {
    int bid = blockIdx.x;            // 0..1023
    int b = bid >> 6;
    int hq = bid & 63;
    int wid = threadIdx.x >> 6, lane = threadIdx.x & 63;
    int h = hq * 4 + wid;
    const float* q = query + b * QDIM;
    const float* w = W1 + (size_t)h * (DDIM + QDIM) + DDIM;
    float s = 0.f;
    #pragma unroll 4
    for (int k = lane; k < QDIM; k += 64) s += q[k] * w[k];
    #pragma unroll
    for (int o = 32; o; o >>= 1) s += __shfl_down(s, o);
    if (lane == 0) qproj[b * HDIM + h] = s + b1[h];
}

// ---------------- K0b: Wc -> bf16 (pre-swizzled chunks), w2 ----------------
__global__ __launch_bounds__(256) void k_prepw(const float* __restrict__ W1,
                                               const float* __restrict__ v,
                                               const float* __restrict__ g,
                                               unsigned short* __restrict__ Wc_sw,
                                               float* __restrict__ w2) {
    int bid = blockIdx.x;
    if (bid < HDIM) {
        int h = bid;
        const float* src = W1 + (size_t)h * (DDIM + QDIM);
        int hx = h & 7;
        for (int d = threadIdx.x; d < DDIM; d += 256) {
            int kt = d >> 6;
            int s  = (d >> 3) & 7;      // 16B chunk within 64-col k-tile
            int dl = d & 7;
            int dp = (kt << 6) + ((s ^ hx) << 3) + dl;
            Wc_sw[h * DDIM + dp] = f2bf(src[d]);
        }
    } else {
        __shared__ float red[256];
        float vv = (threadIdx.x < HDIM) ? v[threadIdx.x] : 0.f;
        red[threadIdx.x] = vv * vv;
        __syncthreads();
        for (int o = 128; o; o >>= 1) {
            if (threadIdx.x < o) red[threadIdx.x] += red[threadIdx.x + o];
            __syncthreads();
        }
        float nrm = sqrtf(red[0]);
        if (threadIdx.x < HDIM) w2[threadIdx.x] = g[0] * vv / nrm;
    }
}

// ---------------- K2: score[b][l] (bf16 MFMA GEMM + tanh + h-reduce) ----------------
__global__ __launch_bounds__(256, 3) void k_score(const float* __restrict__ ctx,
                                                  const unsigned short* __restrict__ Wc_sw,
                                                  const float* __restrict__ qproj,
                                                  const float* __restrict__ w2,
                                                  const float* __restrict__ b2,
                                                  const int* __restrict__ mask,
                                                  float* __restrict__ score_out) {
    __shared__ unsigned short At[64 * 64];    // 8 KB, XOR-swizzled
    __shared__ unsigned short Wt[256 * 64];   // 32 KB, pre-swizzled in global
    int tid = threadIdx.x;
    int wid = tid >> 6, lane = tid & 63;
    int hl = lane & 15, lhi = lane >> 4;
    int bid = blockIdx.x;
    int row0 = bid * 64;
    int b = row0 >> 11;

    float qp[4], wv[4];
    #pragma unroll
    for (int ht = 0; ht < 4; ht++) {
        int h = wid * 64 + ht * 16 + hl;
        qp[ht] = qproj[b * HDIM + h];
        wv[ht] = w2[h];
    }

    f32x4 acc[4][4];
    #pragma unroll
    for (int mt = 0; mt < 4; mt++)
        #pragma unroll
        for (int ht = 0; ht < 4; ht++)
            acc[mt][ht] = (f32x4){0.f, 0.f, 0.f, 0.f};

    int srow = tid >> 2;            // 0..63 tile row this thread stages
    int scol = (tid & 3) * 16;      // 0,16,32,48 within 64-col k-tile
    const float* csrc = ctx + (size_t)(row0 + srow) * DDIM + scol;
    int c0 = (tid & 3) * 2;         // first 16B chunk index
    int sx = srow & 7;

    for (int kt = 0; kt < 16; kt++) {
        // stage W tile: 32 KB via global_load_lds (linear dest; src pre-swizzled)
        #pragma unroll
        for (int i = 0; i < 8; i++) {
            int n = i * 256 + tid;
            const unsigned short* gsrc = Wc_sw + (size_t)(n >> 3) * DDIM + kt * 64 + (n & 7) * 8;
            __builtin_amdgcn_global_load_lds(
                (const __attribute__((address_space(1))) unsigned int*)gsrc,
                (__attribute__((address_space(3))) unsigned int*)(Wt + (i * 256 + (tid & ~63)) * 8),
                16, 0, 0);
        }
        // stage ctx tile: f32 -> bf16 -> swizzled LDS
        const float* cp = csrc + kt * 64;
        float4 cv0 = *(const float4*)(cp + 0);
        float4 cv1 = *(const float4*)(cp + 4);
        float4 cv2 = *(const float4*)(cp + 8);
        float4 cv3 = *(const float4*)(cp + 12);
        short8 p0 = { (short)f2bf(cv0.x), (short)f2bf(cv0.y), (short)f2bf(cv0.z), (short)f2bf(cv0.w),
                      (short)f2bf(cv1.x), (short)f2bf(cv1.y), (short)f2bf(cv1.z), (short)f2bf(cv1.w) };
        short8 p1 = { (short)f2bf(cv2.x), (short)f2bf(cv2.y), (short)f2bf(cv2.z), (short)f2bf(cv2.w),
                      (short)f2bf(cv3.x), (short)f2bf(cv3.y), (short)f2bf(cv3.z), (short)f2bf(cv3.w) };
        *(short8*)(At + srow * 64 + (((c0 + 0) ^ sx) << 3)) = p0;
        *(short8*)(At + srow * 64 + (((c0 + 1) ^ sx) << 3)) = p1;
        __syncthreads();

        #pragma unroll
        for (int ks = 0; ks < 2; ks++) {
            int s = ks * 4 + lhi;
            short8 af[4], bfr[4];
            #pragma unroll
            for (int mt = 0; mt < 4; mt++) {
                int m = mt * 16 + hl;
                af[mt] = *(const short8*)(At + m * 64 + ((s ^ (m & 7)) << 3));
            }
            #pragma unroll
            for (int ht = 0; ht < 4; ht++) {
                int h = wid * 64 + ht * 16 + hl;
                bfr[ht] = *(const short8*)(Wt + h * 64 + ((s ^ (h & 7)) << 3));
            }
            #pragma unroll
            for (int mt = 0; mt < 4; mt++)
                #pragma unroll
                for (int ht = 0; ht < 4; ht++)
                    acc[mt][ht] = __builtin_amdgcn_mfma_f32_16x16x32_bf16(af[mt], bfr[ht], acc[mt][ht], 0, 0, 0);
        }
        __syncthreads();
    }

    // epilogue: tanh + w2 dot, reduce 16 lanes, cross-wave via LDS
    float* sb = (float*)At;   // reuse (last loop iter ended with barrier)
    #pragma unroll
    for (int mt = 0; mt < 4; mt++) {
        #pragma unroll
        for (int r = 0; r < 4; r++) {
            float partial = 0.f;
            #pragma unroll
            for (int ht = 0; ht < 4; ht++) {
                float x = acc[mt][ht][r] + qp[ht];
                x = fminf(fmaxf(x, -15.f), 15.f);
                float e = __expf(2.f * x);
                partial += (e - 1.f) / (e + 1.f) * wv[ht];
            }
            #pragma unroll
            for (int o = 1; o < 16; o <<= 1) partial += __shfl_xor(partial, o);
            if (hl == 0) sb[wid * 64 + mt * 16 + lhi * 4 + r] = partial;
        }
    }
    __syncthreads();
    if (tid < 64) {
        float s = sb[tid] + sb[64 + tid] + sb[128 + tid] + sb[192 + tid] + b2[0];
        int grow = row0 + tid;
        int bb = grow >> 11, ll = grow & 2047;
        if (mask[bb * 2048 + ll] == 1) s = NEGV;
        score_out[grow] = s;
    }
}

// ---------------- K3: softmax in-place per batch row ----------------
__global__ __launch_bounds__(256) void k_softmax(float* __restrict__ p) {
    int b = blockIdx.x;
    float* row = p + b * LCTX;
    __shared__ float red[256];
    float vals[8];
    float mx = -1e30f;
    #pragma unroll
    for (int i = 0; i < 8; i++) { vals[i] = row[threadIdx.x + i * 256]; mx = fmaxf(mx, vals[i]); }
    red[threadIdx.x] = mx;
    __syncthreads();
    for (int o = 128; o; o >>= 1) {
        if (threadIdx.x < o) red[threadIdx.x] = fmaxf(red[threadIdx.x], red[threadIdx.x + o]);
        __syncthreads();
    }
    mx = red[0];
    __syncthreads();
    float sum = 0.f;
    #pragma unroll
    for (int i = 0; i < 8; i++) { vals[i] = __expf(vals[i] - mx); sum += vals[i]; }
    red[threadIdx.x] = sum;
    __syncthreads();
    for (int o = 128; o; o >>= 1) {
        if (threadIdx.x < o) red[threadIdx.x] += red[threadIdx.x + o];
        __syncthreads();
    }
    float inv = 1.f / red[0];
    #pragma unroll
    for (int i = 0; i < 8; i++) row[threadIdx.x + i * 256] = vals[i] * inv;
}

// ---------------- K4: partial expected_ctx over l-splits ----------------
__global__ __launch_bounds__(256) void k_expected(const float* __restrict__ ctx,
                                                  const float* __restrict__ p,
                                                  float* __restrict__ part) {
    int b = blockIdx.x, dc = blockIdx.y, ls = blockIdx.z;
    int t = threadIdx.x;
    int dd = (t & 31) * 4;
    int lp = t >> 5;
    const float* base = ctx + (size_t)b * LCTX * DDIM + dc * 128 + dd;
    const float* pr = p + b * LCTX + ls * 256;
    float4 a = {0.f, 0.f, 0.f, 0.f};
    #pragma unroll 4
    for (int k = 0; k < 32; k++) {
        int l = lp + k * 8;
        float w = pr[l];
        float4 c = *(const float4*)(base + (size_t)(ls * 256 + l) * DDIM);
        a.x += w * c.x; a.y += w * c.y; a.z += w * c.z; a.w += w * c.w;
    }
    __shared__ float red[8][128];
    red[lp][dd + 0] = a.x; red[lp][dd + 1] = a.y; red[lp][dd + 2] = a.z; red[lp][dd + 3] = a.w;
    __syncthreads();
    if (t < 128) {
        float s = 0.f;
        #pragma unroll
        for (int i = 0; i < 8; i++) s += red[i][t];
        part[((size_t)ls * 16 + b) * DDIM + dc * 128 + t] = s;
    }
}

// ---------------- K5: reduce l-split partials ----------------
__global__ __launch_bounds__(256) void k_finish(const float* __restrict__ part,
                                                float* __restrict__ out) {
    int idx = blockIdx.x * 256 + threadIdx.x;   // < 16384
    float s = 0.f;
    #pragma unroll
    for (int i = 0; i < 8; i++) s += part[i * 16384 + idx];
    out[idx] = s;
}

extern "C" void kernel_launch(void* const* d_in, const int* in_sizes, int n_in,
                              void* d_out, int out_size, void* d_ws, size_t ws_size,
                              hipStream_t stream) {
    const float* ctx   = (const float*)d_in[0];
    const float* query = (const float*)d_in[1];
    const int*   mask  = (const int*)d_in[2];
    const float* W1    = (const float*)d_in[3];
    const float* b1    = (const float*)d_in[4];
    const float* v     = (const float*)d_in[5];
    const float* g     = (const float*)d_in[6];
    const float* b2    = (const float*)d_in[7];
    float* out_exp = (float*)d_out;              // [16,1024]
    float* out_p   = (float*)d_out + 16384;      // [16,2048]

    char* ws = (char*)d_ws;
    unsigned short* Wc_sw = (unsigned short*)ws;          // 512 KB
    float* qproj = (float*)(ws + 524288);                 // 16 KB
    float* w2    = (float*)(ws + 540672);                 // 1 KB
    float* part  = (float*)(ws + 541696);                 // 512 KB

    k_qproj  <<<dim3(1024),    256, 0, stream>>>(query, W1, b1, qproj);
    k_prepw  <<<dim3(257),     256, 0, stream>>>(W1, v, g, Wc_sw, w2);
    k_score  <<<dim3(512),     256, 0, stream>>>(ctx, Wc_sw, qproj, w2, b2, mask, out_p);
    k_softmax<<<dim3(16),      256, 0, stream>>>(out_p);
    k_expected<<<dim3(16, 8, 8), 256, 0, stream>>>(ctx, out_p, part);
    k_finish <<<dim3(64),      256, 0, stream>>>(part, out_exp);
}

// Round 2
// 59.149 us; speedup vs baseline: 1.1916x; 1.1916x over previous
//
#include <hip/hip_runtime.h>
#include <hip/hip_bf16.h>

#define BB 16
#define LCTX 2048
#define DDIM 1024
#define QDIM 1024
#define HDIM 256
#define NEGV -10000.0f

typedef __attribute__((ext_vector_type(8))) short short8;
typedef __attribute__((ext_vector_type(4))) float f32x4;

__device__ inline unsigned short f2bf(float x) {
    unsigned int u = __float_as_uint(x);
    unsigned int r = (u + 0x7fffu + ((u >> 16) & 1u)) >> 16;
    return (unsigned short)r;
}

// ---------------- K1: fused prep ----------------
// bid <  1024 : qproj[b][h] = query[b] . Wq[h] + b1[h]   (4 h per block)
// 1024..1279  : Wc row (h = bid-1024) -> bf16, chunks pre-swizzled for LDS
// bid == 1280 : w2 = g * v / ||v||
__global__ __launch_bounds__(256) void k_prep(const float* __restrict__ query,
                                              const float* __restrict__ W1,
                                              const float* __restrict__ b1,
                                              const float* __restrict__ v,
                                              const float* __restrict__ g,
                                              float* __restrict__ qproj,
                                              unsigned short* __restrict__ Wc_sw,
                                              float* __restrict__ w2) {
    int bid = blockIdx.x;
    if (bid < 1024) {
        int b = bid >> 6;
        int hq = bid & 63;
        int wid = threadIdx.x >> 6, lane = threadIdx.x & 63;
        int h = hq * 4 + wid;
        const float* q = query + b * QDIM;
        const float* w = W1 + (size_t)h * (DDIM + QDIM) + DDIM;
        float s = 0.f;
        #pragma unroll 4
        for (int k = lane; k < QDIM; k += 64) s += q[k] * w[k];
        #pragma unroll
        for (int o = 32; o; o >>= 1) s += __shfl_down(s, o);
        if (lane == 0) qproj[b * HDIM + h] = s + b1[h];
    } else if (bid < 1280) {
        int h = bid - 1024;
        const float* src = W1 + (size_t)h * (DDIM + QDIM);
        int hx = h & 7;
        for (int d = threadIdx.x; d < DDIM; d += 256) {
            int kt = d >> 6;
            int s  = (d >> 3) & 7;      // 16B chunk within 64-col k-tile
            int dl = d & 7;
            int dp = (kt << 6) + ((s ^ hx) << 3) + dl;
            Wc_sw[h * DDIM + dp] = f2bf(src[d]);
        }
    } else {
        __shared__ float red[256];
        float vv = (threadIdx.x < HDIM) ? v[threadIdx.x] : 0.f;
        red[threadIdx.x] = vv * vv;
        __syncthreads();
        for (int o = 128; o; o >>= 1) {
            if (threadIdx.x < o) red[threadIdx.x] += red[threadIdx.x + o];
            __syncthreads();
        }
        float nrm = sqrtf(red[0]);
        if (threadIdx.x < HDIM) w2[threadIdx.x] = g[0] * vv / nrm;
    }
}

// ---------------- K2: score GEMM + tanh + exp + partial expected-ctx GEMV ----------------
__global__ __launch_bounds__(256, 3) void k_score(const float* __restrict__ ctx,
                                                  const unsigned short* __restrict__ Wc_sw,
                                                  const float* __restrict__ qproj,
                                                  const float* __restrict__ w2,
                                                  const float* __restrict__ b2,
                                                  const int* __restrict__ mask,
                                                  float* __restrict__ e_ws,
                                                  float* __restrict__ esum_ws,
                                                  float* __restrict__ part) {
    __shared__ unsigned short At[64 * 64];    // 8 KB, XOR-swizzled
    __shared__ unsigned short Wt[256 * 64];   // 32 KB, pre-swizzled in global
    int tid = threadIdx.x;
    int wid = tid >> 6, lane = tid & 63;
    int hl = lane & 15, lhi = lane >> 4;
    int bid = blockIdx.x;
    int row0 = bid * 64;
    int b = row0 >> 11;

    float qp[4], wv[4];
    #pragma unroll
    for (int ht = 0; ht < 4; ht++) {
        int h = wid * 64 + ht * 16 + hl;
        qp[ht] = qproj[b * HDIM + h];
        wv[ht] = w2[h];
    }

    f32x4 acc[4][4];
    #pragma unroll
    for (int mt = 0; mt < 4; mt++)
        #pragma unroll
        for (int ht = 0; ht < 4; ht++)
            acc[mt][ht] = (f32x4){0.f, 0.f, 0.f, 0.f};

    int srow = tid >> 2;            // 0..63 tile row this thread stages
    int scol = (tid & 3) * 16;      // 0,16,32,48 within 64-col k-tile
    const float* csrc = ctx + (size_t)(row0 + srow) * DDIM + scol;
    int c0 = (tid & 3) * 2;         // first 16B chunk index
    int sx = srow & 7;

    for (int kt = 0; kt < 16; kt++) {
        // stage W tile: 32 KB via global_load_lds (linear dest; src pre-swizzled)
        #pragma unroll
        for (int i = 0; i < 8; i++) {
            int n = i * 256 + tid;
            const unsigned short* gsrc = Wc_sw + (size_t)(n >> 3) * DDIM + kt * 64 + (n & 7) * 8;
            __builtin_amdgcn_global_load_lds(
                (const __attribute__((address_space(1))) unsigned int*)gsrc,
                (__attribute__((address_space(3))) unsigned int*)(Wt + (i * 256 + (tid & ~63)) * 8),
                16, 0, 0);
        }
        // stage ctx tile: f32 -> bf16 -> swizzled LDS
        const float* cp = csrc + kt * 64;
        float4 cv0 = *(const float4*)(cp + 0);
        float4 cv1 = *(const float4*)(cp + 4);
        float4 cv2 = *(const float4*)(cp + 8);
        float4 cv3 = *(const float4*)(cp + 12);
        short8 p0 = { (short)f2bf(cv0.x), (short)f2bf(cv0.y), (short)f2bf(cv0.z), (short)f2bf(cv0.w),
                      (short)f2bf(cv1.x), (short)f2bf(cv1.y), (short)f2bf(cv1.z), (short)f2bf(cv1.w) };
        short8 p1 = { (short)f2bf(cv2.x), (short)f2bf(cv2.y), (short)f2bf(cv2.z), (short)f2bf(cv2.w),
                      (short)f2bf(cv3.x), (short)f2bf(cv3.y), (short)f2bf(cv3.z), (short)f2bf(cv3.w) };
        *(short8*)(At + srow * 64 + (((c0 + 0) ^ sx) << 3)) = p0;
        *(short8*)(At + srow * 64 + (((c0 + 1) ^ sx) << 3)) = p1;
        __syncthreads();

        #pragma unroll
        for (int ks = 0; ks < 2; ks++) {
            int s = ks * 4 + lhi;
            short8 af[4], bfr[4];
            #pragma unroll
            for (int mt = 0; mt < 4; mt++) {
                int m = mt * 16 + hl;
                af[mt] = *(const short8*)(At + m * 64 + ((s ^ (m & 7)) << 3));
            }
            #pragma unroll
            for (int ht = 0; ht < 4; ht++) {
                int h = wid * 64 + ht * 16 + hl;
                bfr[ht] = *(const short8*)(Wt + h * 64 + ((s ^ (h & 7)) << 3));
            }
            #pragma unroll
            for (int mt = 0; mt < 4; mt++)
                #pragma unroll
                for (int ht = 0; ht < 4; ht++)
                    acc[mt][ht] = __builtin_amdgcn_mfma_f32_16x16x32_bf16(af[mt], bfr[ht], acc[mt][ht], 0, 0, 0);
        }
        __syncthreads();
    }

    // ---- epilogue 1: tanh + w2 dot, reduce 16 lanes, cross-wave via LDS ----
    float* sb  = (float*)At;        // 256 floats (cross-wave partials)
    float* sbe = sb + 256;          // 64 floats (e per row)
    #pragma unroll
    for (int mt = 0; mt < 4; mt++) {
        #pragma unroll
        for (int r = 0; r < 4; r++) {
            float partial = 0.f;
            #pragma unroll
            for (int ht = 0; ht < 4; ht++) {
                float x = acc[mt][ht][r] + qp[ht];
                x = fminf(fmaxf(x, -15.f), 15.f);
                float e = __expf(2.f * x);
                partial += (e - 1.f) / (e + 1.f) * wv[ht];
            }
            #pragma unroll
            for (int o = 1; o < 16; o <<= 1) partial += __shfl_xor(partial, o);
            if (hl == 0) sb[wid * 64 + mt * 16 + lhi * 4 + r] = partial;
        }
    }
    __syncthreads();

    // ---- epilogue 2: final score -> e = exp(score) (masked -> 0), wave 0 only ----
    if (tid < 64) {
        float s = sb[tid] + sb[64 + tid] + sb[128 + tid] + sb[192 + tid] + b2[0];
        int grow = row0 + tid;
        int bb = grow >> 11, ll = grow & 2047;
        float e = (mask[bb * 2048 + ll] == 1) ? 0.f : __expf(s);
        e_ws[grow] = e;
        sbe[tid] = e;
        float tot = e;
        #pragma unroll
        for (int o = 32; o; o >>= 1) tot += __shfl_down(tot, o);
        if (tid == 0) esum_ws[bid] = tot;
    }
    __syncthreads();

    // ---- epilogue 3: partial GEMV  part[bid][d] = sum_l e_l * ctx[row0+l][d] ----
    // re-reads the block's own 64x1024 f32 tile (256 KB) -> L2/L3-hot
    {
        int d0 = tid * 4;
        const float* cb = ctx + (size_t)row0 * DDIM + d0;
        float4 a = {0.f, 0.f, 0.f, 0.f};
        #pragma unroll 8
        for (int l = 0; l < 64; l++) {
            float el = sbe[l];
            float4 c = *(const float4*)(cb + (size_t)l * DDIM);
            a.x += el * c.x; a.y += el * c.y; a.z += el * c.z; a.w += el * c.w;
        }
        *(float4*)(part + (size_t)bid * DDIM + d0) = a;
    }
}

// ---------------- K3: normalize -> out_exp, out_p ----------------
__global__ __launch_bounds__(256) void k_norm(const float* __restrict__ e_ws,
                                              const float* __restrict__ esum_ws,
                                              const float* __restrict__ part,
                                              float* __restrict__ out_exp,
                                              float* __restrict__ out_p) {
    int b = blockIdx.x, dc = blockIdx.y;
    int tid = threadIdx.x;
    float se = 0.f;
    #pragma unroll
    for (int j = 0; j < 32; j++) se += esum_ws[b * 32 + j];
    float inv = 1.f / se;
    if (tid < 128) {
        int d = dc * 128 + tid;
        float s = 0.f;
        #pragma unroll
        for (int j = 0; j < 32; j++) s += part[(size_t)(b * 32 + j) * DDIM + d];
        out_exp[b * DDIM + d] = s * inv;
    }
    int l = dc * 256 + tid;
    out_p[b * LCTX + l] = e_ws[b * LCTX + l] * inv;
}

extern "C" void kernel_launch(void* const* d_in, const int* in_sizes, int n_in,
                              void* d_out, int out_size, void* d_ws, size_t ws_size,
                              hipStream_t stream) {
    const float* ctx   = (const float*)d_in[0];
    const float* query = (const float*)d_in[1];
    const int*   mask  = (const int*)d_in[2];
    const float* W1    = (const float*)d_in[3];
    const float* b1    = (const float*)d_in[4];
    const float* v     = (const float*)d_in[5];
    const float* g     = (const float*)d_in[6];
    const float* b2    = (const float*)d_in[7];
    float* out_exp = (float*)d_out;              // [16,1024]
    float* out_p   = (float*)d_out + 16384;      // [16,2048]

    char* ws = (char*)d_ws;
    unsigned short* Wc_sw = (unsigned short*)ws;          // 512 KB
    float* qproj = (float*)(ws + 524288);                 // 16 KB
    float* w2    = (float*)(ws + 540672);                 // 1 KB
    float* e_ws  = (float*)(ws + 541696);                 // 128 KB (16x2048)
    float* esum  = (float*)(ws + 672768);                 // 2 KB  (512)
    float* part  = (float*)(ws + 674816);                 // 2 MB  (512x1024)

    k_prep <<<dim3(1281),   256, 0, stream>>>(query, W1, b1, v, g, qproj, Wc_sw, w2);
    k_score<<<dim3(512),    256, 0, stream>>>(ctx, Wc_sw, qproj, w2, b2, mask, e_ws, esum, part);
    k_norm <<<dim3(16, 8),  256, 0, stream>>>(e_ws, esum, part, out_exp, out_p);
}